// Round 9
// baseline (458.076 us; speedup 1.0000x reference)
//
#include <hip/hip_runtime.h>
#include <hip/hip_cooperative_groups.h>
#include <math.h>

namespace cg = cooperative_groups;

#define MROWS 8192   // T*B flat rows
#define DM    512    // d_model
#define SEQL  2048   // attention sequence (rows per batch group)
#define HDIM  64
#define NSPLIT 2     // key-dimension split for attention occupancy

typedef __attribute__((ext_vector_type(4))) float floatx4;
typedef _Float16 half2v __attribute__((ext_vector_type(2)));
typedef _Float16 half4v __attribute__((ext_vector_type(4)));
typedef _Float16 half8v __attribute__((ext_vector_type(8)));

#define CEXP 0.18033688011f   // log2(e)/8 — folded into Wq/bq at transpose time

#define SMEM_BYTES 34816

struct MhaArgs {
    const float *q32, *k32, *v32;
    const float *Wq32, *Wk32, *Wv32, *Wo32;
    const float *bq, *bk, *bv, *bo;
    _Float16 *Wqt, *Wkt, *Wvt, *Wot;
    _Float16 *Q16, *K16, *Vtb, *Opart;
    float *lpart;
    float *out;
};

// async global->LDS, 16B per lane; LDS dst must be uniform_base + lane*16
__device__ __forceinline__ void gll16(const void* g, void* l) {
    __builtin_amdgcn_global_load_lds(
        (const __attribute__((address_space(1))) unsigned int*)g,
        (__attribute__((address_space(3))) unsigned int*)l, 16, 0, 0);
}

__device__ __forceinline__ half4v pack4(float a, float b, float c, float d) {
    half2v lo = __builtin_bit_cast(half2v, __builtin_amdgcn_cvt_pkrtz(a, b));
    half2v hi = __builtin_bit_cast(half2v, __builtin_amdgcn_cvt_pkrtz(c, d));
    half4v r;
    r[0] = lo[0]; r[1] = lo[1]; r[2] = hi[0]; r[3] = hi[1];
    return r;
}

// ============== P0: weight transpose+cast, unit = one 32x32 tile (1024) =====
__device__ __forceinline__ void phase0(const MhaArgs& a, int u, int tid,
                                       unsigned char* smem) {
    float* tile = (float*)smem;  // [32][33]
    const int z = u >> 8, t = u & 255;
    const float* W = z == 0 ? a.Wq32 : (z == 1 ? a.Wk32 : (z == 2 ? a.Wv32 : a.Wo32));
    _Float16* T = z == 0 ? a.Wqt : (z == 1 ? a.Wkt : (z == 2 ? a.Wvt : a.Wot));
    const float sc = (z == 0) ? CEXP : 1.0f;
    const int tx = tid & 31, ty = tid >> 5;          // 32 x 8
    const int x = (t & 15) * 32 + tx;
    const int y0 = (t >> 4) * 32;
    __syncthreads();   // protect tile from previous unit's readers
#pragma unroll
    for (int i = 0; i < 4; ++i)
        tile[(ty + i * 8) * 33 + tx] = W[(size_t)(y0 + ty + i * 8) * DM + x];
    __syncthreads();
    const int xo = y0 + tx;
#pragma unroll
    for (int i = 0; i < 4; ++i)
        T[(size_t)((t & 15) * 32 + ty + i * 8) * DM + xo] =
            (_Float16)(tile[tx * 33 + ty + i * 8] * sc);
}

// ============== P1: projection GEMM, unit = 32 m-rows x one matrix (768) ====
__device__ __forceinline__ void phase1(const MhaArgs& a, int u, int tid,
                                       unsigned char* smem) {
    _Float16* Bs = (_Float16*)smem;             // 512 x 32 (32 KB)
    _Float16* As = (_Float16*)(smem + 32768);   // 32 x 32  (2 KB)
    const int w = tid >> 6;
    const int l15 = tid & 15, quad = (tid & 63) >> 4;
    const int z = u >> 8;                       // 0=q 1=k 2=v
    const int m0 = (u & 255) * 32;
    const float* A32   = z == 0 ? a.q32 : (z == 1 ? a.k32 : a.v32);
    const _Float16* Bt = z == 0 ? a.Wqt : (z == 1 ? a.Wkt : a.Wvt);
    const float* bias  = z == 0 ? a.bq : (z == 1 ? a.bk : a.bv);
    const float bscale = z == 0 ? CEXP : 1.0f;

    floatx4 acc[2][8];
#pragma unroll
    for (int i = 0; i < 2; ++i)
#pragma unroll
        for (int j = 0; j < 8; ++j) acc[i][j] = (floatx4){0.f, 0.f, 0.f, 0.f};

    for (int kt = 0; kt < DM / 32; ++kt) {   // 16 iters
        __syncthreads();
#pragma unroll
        for (int i = 0; i < 8; ++i) {        // B: 2048 chunks
            const int c = i * 256 + tid;
            const int row = c >> 2, g = c & 3;
            const int kg = g ^ (row & 3);
            gll16(&Bt[(size_t)row * DM + kt * 32 + kg * 8], &Bs[c * 8]);
        }
        if (tid < 128) {                     // A: 128 chunks, f32->f16 fused
            const int c = tid;
            const int row = c >> 2, g = c & 3;
            const int kg = g ^ (row & 3);
            const float* src = &A32[(size_t)(m0 + row) * DM + kt * 32 + kg * 8];
            const float4 f0 = *(const float4*)&src[0];
            const float4 f1 = *(const float4*)&src[4];
            half8v o;
            o[0] = (_Float16)f0.x; o[1] = (_Float16)f0.y; o[2] = (_Float16)f0.z; o[3] = (_Float16)f0.w;
            o[4] = (_Float16)f1.x; o[5] = (_Float16)f1.y; o[6] = (_Float16)f1.z; o[7] = (_Float16)f1.w;
            *(half8v*)&As[c * 8] = o;
        }
        __syncthreads();
        half8v af[2], bfr[8];
#pragma unroll
        for (int i = 0; i < 2; ++i) {
            const int row = i * 16 + l15;
            af[i] = *(const half8v*)&As[row * 32 + (quad ^ (row & 3)) * 8];
        }
#pragma unroll
        for (int j = 0; j < 8; ++j) {
            const int row = w * 128 + j * 16 + l15;
            bfr[j] = *(const half8v*)&Bs[row * 32 + (quad ^ (row & 3)) * 8];
        }
#pragma unroll
        for (int i = 0; i < 2; ++i)
#pragma unroll
            for (int j = 0; j < 8; ++j)
                acc[i][j] = __builtin_amdgcn_mfma_f32_16x16x32_f16(af[i], bfr[j], acc[i][j], 0, 0, 0);
    }
#pragma unroll
    for (int j = 0; j < 8; ++j) {
        const int col = w * 128 + j * 16 + l15;
        const float bv4 = bias[col] * bscale;
#pragma unroll
        for (int i = 0; i < 2; ++i) {
            const int rb = m0 + i * 16 + quad * 4;
            if (z == 2) {   // Vt[g][col][seq]
                const int g = rb >> 11, seq = rb & 2047;
                half4v pv;
#pragma unroll
                for (int r = 0; r < 4; ++r) pv[r] = (_Float16)(acc[i][j][r] + bv4);
                *(half4v*)&a.Vtb[((size_t)g * DM + col) * SEQL + seq] = pv;
            } else {
                _Float16* oh = z == 0 ? a.Q16 : a.K16;
#pragma unroll
                for (int r = 0; r < 4; ++r)
                    oh[(size_t)(rb + r) * DM + col] = (_Float16)(acc[i][j][r] + bv4);
            }
        }
    }
}

// ============== P2: split-K flash attention, unit = (qtile,pair,split) ======
__device__ __forceinline__ void phase2(const MhaArgs& a, int u, int tid,
                                       unsigned char* smem) {
    _Float16* KsB = (_Float16*)smem;             // 2 x 4096
    _Float16* VsB = (_Float16*)(smem + 16384);   // 2 x 4096
    const int w = tid >> 6;
    const int l15 = tid & 15, quad = (tid & 63) >> 4;

    const int qtile = u & 15;
    const int pair  = (u >> 4) & 31;
    const int split = u >> 9;
    const int grp   = pair >> 3;
    const int h     = pair & 7;
    const int q0    = qtile * 128;
    const int rQ    = grp * SEQL + q0 + w * 32;
    const int cb    = h * HDIM;
    const int NIT   = (SEQL / 64) / NSPLIT;   // 16
    const int kt0   = split * NIT;

    const _Float16* Kbase = a.K16 + (size_t)grp * SEQL * DM + cb;
    const _Float16* Vbase = a.Vtb + (size_t)grp * DM * SEQL + (size_t)cb * SEQL;

    half8v qf[2][2];
#pragma unroll
    for (int qt = 0; qt < 2; ++qt)
#pragma unroll
        for (int ks = 0; ks < 2; ++ks)
            qf[qt][ks] = *(const half8v*)&a.Q16[(size_t)(rQ + qt * 16 + l15) * DM + cb + ks * 32 + quad * 8];

    floatx4 oacc[2][4], lacc[2];
#pragma unroll
    for (int qt = 0; qt < 2; ++qt) {
        lacc[qt] = (floatx4){0.f, 0.f, 0.f, 0.f};
#pragma unroll
        for (int dt = 0; dt < 4; ++dt) oacc[qt][dt] = (floatx4){0.f, 0.f, 0.f, 0.f};
    }
    half4v ones;
    ones[0] = (_Float16)1.f; ones[1] = (_Float16)1.f; ones[2] = (_Float16)1.f; ones[3] = (_Float16)1.f;

#define STAGE(KT, B)                                                            \
    {                                                                           \
        _Float16* ksb = &KsB[(B) * 4096];                                       \
        _Float16* vsb = &VsB[(B) * 4096];                                       \
        _Pragma("unroll")                                                       \
        for (int i_ = 0; i_ < 4; ++i_) {                                        \
            const int c_ = i_ * 256 + tid;                                      \
            if (c_ < 512) {                                                     \
                const int key_ = c_ >> 3, g_ = c_ & 7;                          \
                const int dg_ = g_ ^ (key_ & 7);                                \
                gll16(&Kbase[(size_t)((KT) * 64 + key_) * DM + dg_ * 8],        \
                      &ksb[c_ * 8]);                                            \
            } else {                                                            \
                const int cv_ = c_ - 512;                                       \
                const int d_ = cv_ >> 3, g_ = cv_ & 7;                          \
                const int kg_ = g_ ^ (d_ & 7);                                  \
                gll16(&Vbase[(size_t)d_ * SEQL + (KT) * 64 + kg_ * 8],          \
                      &vsb[cv_ * 8]);                                           \
            }                                                                   \
        }                                                                       \
    }

    STAGE(kt0, 0)

    for (int it = 0; it < NIT; ++it) {
        const int cur = it & 1;
        __syncthreads();
        if (it + 1 < NIT) STAGE(kt0 + it + 1, cur ^ 1)

        const _Float16* ksb = &KsB[cur * 4096];
        const _Float16* vsb = &VsB[cur * 4096];

        floatx4 st[4][2];
#pragma unroll
        for (int ktile = 0; ktile < 4; ++ktile) {
            const int key = ktile * 16 + l15;
            const half8v kf0 = *(const half8v*)&ksb[key * 64 + ((0 + quad) ^ (key & 7)) * 8];
            const half8v kf1 = *(const half8v*)&ksb[key * 64 + ((4 + quad) ^ (key & 7)) * 8];
#pragma unroll
            for (int qt = 0; qt < 2; ++qt) {
                floatx4 z2 = {0.f, 0.f, 0.f, 0.f};
                z2 = __builtin_amdgcn_mfma_f32_16x16x32_f16(kf0, qf[qt][0], z2, 0, 0, 0);
                st[ktile][qt] = __builtin_amdgcn_mfma_f32_16x16x32_f16(kf1, qf[qt][1], z2, 0, 0, 0);
            }
        }

        half4v pa[4][2];
#pragma unroll
        for (int ktile = 0; ktile < 4; ++ktile)
#pragma unroll
            for (int qt = 0; qt < 2; ++qt)
                pa[ktile][qt] = pack4(__builtin_amdgcn_exp2f(st[ktile][qt][0]),
                                      __builtin_amdgcn_exp2f(st[ktile][qt][1]),
                                      __builtin_amdgcn_exp2f(st[ktile][qt][2]),
                                      __builtin_amdgcn_exp2f(st[ktile][qt][3]));

#pragma unroll
        for (int qt = 0; qt < 2; ++qt)
#pragma unroll
            for (int ktile = 0; ktile < 4; ++ktile)
                lacc[qt] = __builtin_amdgcn_mfma_f32_16x16x16f16(pa[ktile][qt], ones, lacc[qt], 0, 0, 0);

#pragma unroll
        for (int dt = 0; dt < 4; ++dt) {
            const int d = dt * 16 + l15;
#pragma unroll
            for (int ktile = 0; ktile < 4; ++ktile) {
                const int G = ktile * 2 + (quad >> 1);
                const int slot = G ^ (d & 7);
                const half4v vf = *(const half4v*)&vsb[d * 64 + slot * 8 + (quad & 1) * 4];
#pragma unroll
                for (int qt = 0; qt < 2; ++qt)
                    oacc[qt][dt] = __builtin_amdgcn_mfma_f32_16x16x16f16(pa[ktile][qt], vf, oacc[qt][dt], 0, 0, 0);
            }
        }
    }
#undef STAGE

    _Float16* Op = a.Opart + (size_t)split * MROWS * DM;
#pragma unroll
    for (int qt = 0; qt < 2; ++qt)
#pragma unroll
        for (int r = 0; r < 4; ++r) {
            const int qrow = rQ + qt * 16 + quad * 4 + r;
            const size_t rowoff = (size_t)qrow * DM + cb;
#pragma unroll
            for (int dt = 0; dt < 4; ++dt)
                Op[rowoff + dt * 16 + l15] = (_Float16)oacc[qt][dt][r];
            if (l15 == 0)
                a.lpart[((size_t)split * MROWS + qrow) * 8 + h] = lacc[qt][r];
        }
}

// ============== P3: combine + output GEMM, unit = 32m x 128n (1024) =========
__device__ __forceinline__ void phase3(const MhaArgs& a, int u, int tid,
                                       unsigned char* smem) {
    _Float16* Bs = (_Float16*)smem;             // 128 x 64 (16 KB)
    _Float16* As = (_Float16*)(smem + 16384);   // 32 x 64  (4 KB)
    const int w = tid >> 6;
    const int l15 = tid & 15, quad = (tid & 63) >> 4;
    const int n0 = (u & 3) * 128;
    const int m0 = (u >> 2) * 32;

    floatx4 acc[2][2];
#pragma unroll
    for (int i = 0; i < 2; ++i)
#pragma unroll
        for (int j = 0; j < 2; ++j) acc[i][j] = (floatx4){0.f, 0.f, 0.f, 0.f};

    for (int kt = 0; kt < DM / 64; ++kt) {   // 8 iters; head = kt
        __syncthreads();
#pragma unroll
        for (int i = 0; i < 4; ++i) {        // B: 1024 chunks
            const int c = i * 256 + tid;
            const int row = c >> 3, g = c & 7;
            const int kg = g ^ (row & 7);
            gll16(&a.Wot[(size_t)(n0 + row) * DM + kt * 64 + kg * 8], &Bs[c * 8]);
        }
        {                                    // A: 256 chunks, fused combine
            const int c = tid;
            const int row = c >> 3, g = c & 7;
            const int kg = g ^ (row & 7);
            const int grow = m0 + row;
            const size_t off = (size_t)grow * DM + kt * 64 + kg * 8;
            const half8v av = *(const half8v*)&a.Opart[off];
            const half8v bv = *(const half8v*)&a.Opart[(size_t)MROWS * DM + off];
            const float inv = 1.0f / (a.lpart[(size_t)grow * 8 + kt] +
                                      a.lpart[((size_t)MROWS + grow) * 8 + kt]);
            half8v s;
#pragma unroll
            for (int e = 0; e < 8; ++e)
                s[e] = (_Float16)(((float)av[e] + (float)bv[e]) * inv);
            *(half8v*)&As[c * 8] = s;
        }
        __syncthreads();
#pragma unroll
        for (int ks = 0; ks < 2; ++ks) {
            half8v af[2], bfr[2];
#pragma unroll
            for (int i = 0; i < 2; ++i) {
                const int row = i * 16 + l15;
                af[i] = *(const half8v*)&As[row * 64 + ((ks * 4 + quad) ^ (row & 7)) * 8];
            }
#pragma unroll
            for (int j = 0; j < 2; ++j) {
                const int row = w * 32 + j * 16 + l15;
                bfr[j] = *(const half8v*)&Bs[row * 64 + ((ks * 4 + quad) ^ (row & 7)) * 8];
            }
#pragma unroll
            for (int i = 0; i < 2; ++i)
#pragma unroll
                for (int j = 0; j < 2; ++j)
                    acc[i][j] = __builtin_amdgcn_mfma_f32_16x16x32_f16(af[i], bfr[j], acc[i][j], 0, 0, 0);
        }
    }
#pragma unroll
    for (int j = 0; j < 2; ++j) {
        const int col = n0 + w * 32 + j * 16 + l15;
        const float bv4 = a.bo[col];
#pragma unroll
        for (int i = 0; i < 2; ++i) {
            const int rb = m0 + i * 16 + quad * 4;
#pragma unroll
            for (int r = 0; r < 4; ++r)
                a.out[(size_t)(rb + r) * DM + col] = acc[i][j][r] + bv4;
        }
    }
}

// ---------------------------------------------------------------------------
// Fused cooperative kernel: grid-stride unit loops, grid.sync between phases.
// ---------------------------------------------------------------------------
__global__ __launch_bounds__(256, 4) void fused_mha(MhaArgs a) {
    __shared__ __align__(16) unsigned char smem[SMEM_BYTES];
    cg::grid_group grid = cg::this_grid();
    const int tid = threadIdx.x;
    for (unsigned u = blockIdx.x; u < 1024; u += gridDim.x) phase0(a, u, tid, smem);
    grid.sync();
    for (unsigned u = blockIdx.x; u < 768; u += gridDim.x) phase1(a, u, tid, smem);
    grid.sync();
    for (unsigned u = blockIdx.x; u < 1024; u += gridDim.x) phase2(a, u, tid, smem);
    grid.sync();
    for (unsigned u = blockIdx.x; u < 1024; u += gridDim.x) phase3(a, u, tid, smem);
}

// ---- fallback wrappers (normal launches, one per phase) -------------------
__global__ __launch_bounds__(256, 4) void k_p0(MhaArgs a) {
    __shared__ __align__(16) unsigned char smem[SMEM_BYTES];
    phase0(a, blockIdx.x, threadIdx.x, smem);
}
__global__ __launch_bounds__(256, 4) void k_p1(MhaArgs a) {
    __shared__ __align__(16) unsigned char smem[SMEM_BYTES];
    phase1(a, blockIdx.x, threadIdx.x, smem);
}
__global__ __launch_bounds__(256, 4) void k_p2(MhaArgs a) {
    __shared__ __align__(16) unsigned char smem[SMEM_BYTES];
    phase2(a, blockIdx.x, threadIdx.x, smem);
}
__global__ __launch_bounds__(256, 4) void k_p3(MhaArgs a) {
    __shared__ __align__(16) unsigned char smem[SMEM_BYTES];
    phase3(a, blockIdx.x, threadIdx.x, smem);
}

// ---------------------------------------------------------------------------
extern "C" void kernel_launch(void* const* d_in, const int* in_sizes, int n_in,
                              void* d_out, int out_size, void* d_ws, size_t ws_size,
                              hipStream_t stream) {
    MhaArgs a;
    a.k32  = (const float*)d_in[0];
    a.v32  = (const float*)d_in[1];
    a.q32  = (const float*)d_in[2];
    a.Wk32 = (const float*)d_in[3];
    a.bk   = (const float*)d_in[4];
    a.Wv32 = (const float*)d_in[5];
    a.bv   = (const float*)d_in[6];
    a.Wq32 = (const float*)d_in[7];
    a.bq   = (const float*)d_in[8];
    a.Wo32 = (const float*)d_in[9];
    a.bo   = (const float*)d_in[10];
    a.out  = (float*)d_out;

    const size_t MAT = (size_t)MROWS * DM;   // 4M elems
    a.Q16  = (_Float16*)d_ws;                // 8 MB
    a.K16  = a.Q16 + MAT;                    // 8 MB
    a.Vtb  = a.K16 + MAT;                    // 8 MB
    a.Wqt  = a.Vtb + MAT;                    // 0.5 MB each
    a.Wkt  = a.Wqt + DM * DM;
    a.Wvt  = a.Wkt + DM * DM;
    a.Wot  = a.Wvt + DM * DM;
    a.lpart = (float*)(a.Wot + DM * DM);             // 0.5 MB
    a.Opart = (_Float16*)(a.lpart + 2 * MROWS * 8);  // 16 MB -> 42.5 MB total

    // size the cooperative grid from the kernel's ACTUAL occupancy
    int maxAct = 0;
    hipError_t e = hipOccupancyMaxActiveBlocksPerMultiprocessor(
        &maxAct, (const void*)fused_mha, 256, 0);
    bool coop_ok = (e == hipSuccess) && (maxAct >= 1);
    if (coop_ok) {
        int grid = maxAct * 256;
        if (grid > 1024) grid = 1024;
        void* args[] = {(void*)&a};
        e = hipLaunchCooperativeKernel((const void*)fused_mha, dim3(grid),
                                       dim3(256), args, 0, stream);
        coop_ok = (e == hipSuccess);
    }
    if (!coop_ok) {
        // fallback: 4 normal launches (stream-ordered => same result)
        k_p0<<<dim3(1024), dim3(256), 0, stream>>>(a);
        k_p1<<<dim3(768),  dim3(256), 0, stream>>>(a);
        k_p2<<<dim3(1024), dim3(256), 0, stream>>>(a);
        k_p3<<<dim3(1024), dim3(256), 0, stream>>>(a);
    }
}